// Round 11
// baseline (76.706 us; speedup 1.0000x reference)
//
#include <hip/hip_runtime.h>
#include <math.h>

#define NB 8
#define NA 1024
#define NN 64
#define NF 128
#define NS 64
#define LN2 0.69314718055994530942f
#define HSTR 136   // h (bf16) LDS row stride in elems: 272B rows, balanced b128 reads
#define JSTR 72    // wfT (bf16) row stride in elems: 144B rows, 16B-aligned, cheap banking

typedef __attribute__((ext_vector_type(8))) short bf16x8;
typedef __attribute__((ext_vector_type(4))) float f32x4;
typedef __attribute__((ext_vector_type(4))) unsigned u32x4;
typedef __attribute__((ext_vector_type(2))) unsigned u32x2;

__device__ __forceinline__ float ssp(float x) {
    return fmaxf(x, 0.0f) + __logf(1.0f + __expf(-fabsf(x))) - LN2;
}
__device__ __forceinline__ short f2bf(float f) {      // RNE f32 -> bf16 (cold paths)
    unsigned u = __float_as_uint(f);
    u += 0x7fffu + ((u >> 16) & 1u);
    return (short)(u >> 16);
}
__device__ __forceinline__ unsigned pkbf(float a, float b) {   // packed RNE pair, 1 inst
    unsigned r;
    asm("v_cvt_pk_bf16_f32 %0, %1, %2" : "=v"(r) : "v"(a), "v"(b));
    return r;
}
__device__ __forceinline__ float bf2f(short s) {
    return __uint_as_float(((unsigned)(unsigned short)s) << 16);
}

// ---------------- prep: swizzle weights into MFMA B-fragment order (bf16) ----------------
__device__ __forceinline__ void swz_frag(const float* __restrict__ W, short* __restrict__ Wf, int t) {
    int k = t >> 7, n = t & 127;
    int kt = k >> 5, lg = (k >> 3) & 3, j = k & 7, ntg = n >> 4, col = n & 15;
    Wf[((kt * 8 + ntg) * 64 + (lg * 16 + col)) * 8 + j] = f2bf(W[t]);
}

__global__ __launch_bounds__(256) void k_prep(const float* __restrict__ W1,
                                              const float* __restrict__ W2,
                                              const float* __restrict__ Winf,
                                              const float* __restrict__ Wf2,
                                              const float* __restrict__ Wd,
                                              short* __restrict__ W1f, short* __restrict__ W2f,
                                              short* __restrict__ Winff, short* __restrict__ Wf2f,
                                              short* __restrict__ Wdf) {
    int t = blockIdx.x * 256 + threadIdx.x;   // 16384 threads == NF*NF
    if (t < NS * NF) swz_frag(W1, W1f, t);
    swz_frag(W2, W2f, t);
    swz_frag(Winf, Winff, t);
    swz_frag(Wf2, Wf2f, t);
    swz_frag(Wd, Wdf, t);
}

// ---- staging helper: 32 f32 rows (128 wide) -> bf16 LDS, XOR-swizzled, 256B rows ----
__device__ __forceinline__ void stage32(const float* __restrict__ src, char* __restrict__ dst, int t) {
    int row = t >> 3, seg = t & 7;
    const float4* sp = (const float4*)(src + (size_t)row * NF + seg * 16);
    float4 a = sp[0], b = sp[1], c = sp[2], d = sp[3];
    u32x4 lo = (u32x4){pkbf(a.x, a.y), pkbf(a.z, a.w), pkbf(b.x, b.y), pkbf(b.z, b.w)};
    u32x4 hi = (u32x4){pkbf(c.x, c.y), pkbf(c.z, c.w), pkbf(d.x, d.y), pkbf(d.z, d.w)};
    int base = row * 256 + seg * 32;
    int sw = (row & 7) << 4;
    *(u32x4*)(dst + ((base) ^ sw))      = lo;
    *(u32x4*)(dst + ((base + 16) ^ sw)) = hi;
}

// ---------------- kernel 1: y = x @ W_in2f (no bias), MFMA, M=32/block ----------------
__global__ __launch_bounds__(256) void k_in2f_m(const float* __restrict__ x,
                                                const short* __restrict__ Wf,
                                                float* __restrict__ y) {
    __shared__ __align__(16) char xL[32 * 256];   // 8 KB
    int t = threadIdx.x, lane = t & 63, wid = t >> 6;
    int row0 = blockIdx.x * 32;

    stage32(x + (size_t)row0 * NF, xL, t);
    __syncthreads();

    int rowA = lane & 15, kgrp = lane >> 4, goff = wid * 32;
    f32x4 acc[2][2];
#pragma unroll
    for (int mt = 0; mt < 2; mt++) {
        acc[mt][0] = (f32x4){0.f, 0.f, 0.f, 0.f};
        acc[mt][1] = (f32x4){0.f, 0.f, 0.f, 0.f};
    }
#pragma unroll
    for (int kt = 0; kt < 4; kt++) {
        bf16x8 bf0 = *(const bf16x8*)&Wf[((kt * 8 + wid * 2 + 0) * 64 + lane) * 8];
        bf16x8 bf1 = *(const bf16x8*)&Wf[((kt * 8 + wid * 2 + 1) * 64 + lane) * 8];
#pragma unroll
        for (int mt = 0; mt < 2; mt++) {
            int row = mt * 16 + rowA;
            int byte = (row * 256 + kt * 64 + kgrp * 16) ^ ((row & 7) << 4);
            bf16x8 af = *(const bf16x8*)(xL + byte);
            acc[mt][0] = __builtin_amdgcn_mfma_f32_16x16x32_bf16(af, bf0, acc[mt][0], 0, 0, 0);
            acc[mt][1] = __builtin_amdgcn_mfma_f32_16x16x32_bf16(af, bf1, acc[mt][1], 0, 0, 0);
        }
    }
#pragma unroll
    for (int mt = 0; mt < 2; mt++)
#pragma unroll
        for (int nt = 0; nt < 2; nt++)
#pragma unroll
            for (int r = 0; r < 4; r++)
                y[(size_t)(row0 + mt * 16 + kgrp * 4 + r) * NF + goff + nt * 16 + (lane & 15)] = acc[mt][nt][r];
}

// ---------------- kernel 3: buf = ssp(buf@Wf2+bf2) @ Wd + bd, MFMA, in place, M=32/block ----------------
__global__ __launch_bounds__(256) void k_out_m(float* buf,
                                               const short* __restrict__ Wf2f, const float* __restrict__ bf2,
                                               const short* __restrict__ Wdf, const float* __restrict__ bd) {
    __shared__ __align__(16) char xL[32 * 256];   // 8 KB (agg bf16)
    __shared__ short vL[32 * HSTR];               // 8.5 KB (v bf16)
    int t = threadIdx.x, lane = t & 63, wid = t >> 6;
    int row0 = blockIdx.x * 32;

    stage32(buf + (size_t)row0 * NF, xL, t);
    __syncthreads();

    int rowA = lane & 15, kgrp = lane >> 4, goff = wid * 32;
    int gc0 = goff + (lane & 15), gc1 = gc0 + 16;
    float bb0 = bf2[gc0], bb1 = bf2[gc1];

    // GEMM1: v = ssp(agg @ Wf2 + bf2)
    f32x4 acc[2][2];
#pragma unroll
    for (int mt = 0; mt < 2; mt++) {
        acc[mt][0] = (f32x4){bb0, bb0, bb0, bb0};
        acc[mt][1] = (f32x4){bb1, bb1, bb1, bb1};
    }
#pragma unroll
    for (int kt = 0; kt < 4; kt++) {
        bf16x8 bf0 = *(const bf16x8*)&Wf2f[((kt * 8 + wid * 2 + 0) * 64 + lane) * 8];
        bf16x8 bf1 = *(const bf16x8*)&Wf2f[((kt * 8 + wid * 2 + 1) * 64 + lane) * 8];
#pragma unroll
        for (int mt = 0; mt < 2; mt++) {
            int row = mt * 16 + rowA;
            int byte = (row * 256 + kt * 64 + kgrp * 16) ^ ((row & 7) << 4);
            bf16x8 af = *(const bf16x8*)(xL + byte);
            acc[mt][0] = __builtin_amdgcn_mfma_f32_16x16x32_bf16(af, bf0, acc[mt][0], 0, 0, 0);
            acc[mt][1] = __builtin_amdgcn_mfma_f32_16x16x32_bf16(af, bf1, acc[mt][1], 0, 0, 0);
        }
    }
    // ssp -> vL (bf16, HSTR rows)
#pragma unroll
    for (int mt = 0; mt < 2; mt++)
#pragma unroll
        for (int nt = 0; nt < 2; nt++) {
            int col = goff + nt * 16 + (lane & 15);
            int r0 = mt * 16 + kgrp * 4;
            unsigned p01 = pkbf(ssp(acc[mt][nt][0]), ssp(acc[mt][nt][1]));
            unsigned p23 = pkbf(ssp(acc[mt][nt][2]), ssp(acc[mt][nt][3]));
            vL[(r0 + 0) * HSTR + col] = (short)(p01 & 0xffffu);
            vL[(r0 + 1) * HSTR + col] = (short)(p01 >> 16);
            vL[(r0 + 2) * HSTR + col] = (short)(p23 & 0xffffu);
            vL[(r0 + 3) * HSTR + col] = (short)(p23 >> 16);
        }
    __syncthreads();

    // GEMM2: out = v @ Wd + bd
    float bd0 = bd[gc0], bd1 = bd[gc1];
    f32x4 acc2[2][2];
#pragma unroll
    for (int mt = 0; mt < 2; mt++) {
        acc2[mt][0] = (f32x4){bd0, bd0, bd0, bd0};
        acc2[mt][1] = (f32x4){bd1, bd1, bd1, bd1};
    }
#pragma unroll
    for (int kt = 0; kt < 4; kt++) {
        bf16x8 bf0 = *(const bf16x8*)&Wdf[((kt * 8 + wid * 2 + 0) * 64 + lane) * 8];
        bf16x8 bf1 = *(const bf16x8*)&Wdf[((kt * 8 + wid * 2 + 1) * 64 + lane) * 8];
#pragma unroll
        for (int mt = 0; mt < 2; mt++) {
            bf16x8 af = *(const bf16x8*)&vL[(mt * 16 + rowA) * HSTR + kt * 32 + kgrp * 8];
            acc2[mt][0] = __builtin_amdgcn_mfma_f32_16x16x32_bf16(af, bf0, acc2[mt][0], 0, 0, 0);
            acc2[mt][1] = __builtin_amdgcn_mfma_f32_16x16x32_bf16(af, bf1, acc2[mt][1], 0, 0, 0);
        }
    }
#pragma unroll
    for (int mt = 0; mt < 2; mt++)
#pragma unroll
        for (int nt = 0; nt < 2; nt++)
#pragma unroll
            for (int r = 0; r < 4; r++)
                buf[(size_t)(row0 + mt * 16 + kgrp * 4 + r) * NF + goff + nt * 16 + (lane & 15)] = acc2[mt][nt][r];
}

// ---------------- kernel 2: MFMA filter net + cfconv (wfT layout, shfl epilogue) ----------------
// one block per (b,a); 4 waves, wave wid owns g-slice [wid*32, wid*32+32)
// LDS: fijL [0,8192) | hL [8192,25600) ; wfT (bf16, [g][j], JSTR) overlays [0,18432)
__global__ __launch_bounds__(256) void k_conv(
        const float* __restrict__ fij, const float* __restrict__ rij,
        const int* __restrict__ nbr, const int* __restrict__ nmask,
        const float* __restrict__ y,
        const short* __restrict__ W1f, const float* __restrict__ b1,
        const short* __restrict__ W2f, const float* __restrict__ b2,
        float* __restrict__ agg) {
    __shared__ __align__(16) char smem[8192 + NN * HSTR * 2];   // 25600 B
    __shared__ int cOff[NN];   // compacted neighbor row offset (elems, premul NF); tail zeroed

    short* hL  = (short*)(smem + 8192);
    short* wfT = (short*)smem;

    int t = threadIdx.x;
    int ba = blockIdx.x;
    int b = ba >> 10;
    int lane = t & 63;
    int wid = t >> 6;

    const float* fsrc = fij + (size_t)ba * NN * NS;

    // ---- phase 0: every wave computes the same compaction ballot ----
    unsigned long long bal;
    {
        float r = rij[(size_t)ba * NN + lane];
        int mk = nmask[(size_t)ba * NN + lane];
        bool valid = (mk != 0) && (r <= 5.0f);
        bal = __ballot(valid);
        if (wid == 0) {
            if (valid) {
                int pos = __popcll(bal & ((1ULL << lane) - 1ULL));
                cOff[pos] = nbr[(size_t)ba * NN + lane] << 7;   // * NF
            }
            int V0 = (int)__popcll(bal);
            if (lane >= V0) cOff[lane] = 0;      // safe address for masked tail
        }
    }
    int V = (int)__popcll(bal);
    int MT = (V + 15) >> 4;

    // ---- stage valid f_ij rows (bf16, XOR-swizzled) via compaction scatter ----
    {
        int n = t >> 2;
        if ((bal >> n) & 1ULL) {
            int pos = __popcll(bal & ((1ULL << n) - 1ULL));
            int k0 = (t & 3) * 16;
            const float4* src = (const float4*)(fsrc + (size_t)n * NS + k0);
            float4 a = src[0], bb = src[1], c = src[2], d = src[3];
            u32x4 lo = (u32x4){pkbf(a.x, a.y), pkbf(a.z, a.w), pkbf(bb.x, bb.y), pkbf(bb.z, bb.w)};
            u32x4 hi = (u32x4){pkbf(c.x, c.y), pkbf(c.z, c.w), pkbf(d.x, d.y), pkbf(d.z, d.w)};
            int base = pos * 128 + k0 * 2;
            int sw = (pos & 7) << 4;
            *(u32x4*)(smem + ((base) ^ sw))      = lo;
            *(u32x4*)(smem + ((base + 16) ^ sw)) = hi;
        }
    }
    __syncthreads();   // #1

    int rowA = lane & 15;
    int kgrp = lane >> 4;
    int goff = wid * 32;

    int gc0 = goff + (lane & 15);
    int gc1 = gc0 + 16;
    float b1v0 = b1[gc0], b1v1 = b1[gc1];
    float b2v0 = b2[gc0], b2v1 = b2[gc1];

    // ---- GEMM1: h = ssp(fij_c @ W1 + b1) ----
    f32x4 acc[4][2];
#pragma unroll
    for (int mt = 0; mt < 4; mt++) {
        acc[mt][0] = (f32x4){b1v0, b1v0, b1v0, b1v0};
        acc[mt][1] = (f32x4){b1v1, b1v1, b1v1, b1v1};
    }
#pragma unroll
    for (int kt = 0; kt < 2; kt++) {
        bf16x8 bf0 = *(const bf16x8*)&W1f[((kt * 8 + wid * 2 + 0) * 64 + lane) * 8];
        bf16x8 bf1 = *(const bf16x8*)&W1f[((kt * 8 + wid * 2 + 1) * 64 + lane) * 8];
#pragma unroll
        for (int mt = 0; mt < 4; mt++) {
            if (mt < MT) {
                int row = mt * 16 + rowA;
                int byte = (row * 128 + kt * 64 + kgrp * 16) ^ ((row & 7) << 4);
                bf16x8 af = *(const bf16x8*)(smem + byte);
                acc[mt][0] = __builtin_amdgcn_mfma_f32_16x16x32_bf16(af, bf0, acc[mt][0], 0, 0, 0);
                acc[mt][1] = __builtin_amdgcn_mfma_f32_16x16x32_bf16(af, bf1, acc[mt][1], 0, 0, 0);
            }
        }
    }

    // ssp + store h (bf16) to hL (disjoint from fijL region)
#pragma unroll
    for (int mt = 0; mt < 4; mt++) {
        if (mt < MT) {
#pragma unroll
            for (int nt = 0; nt < 2; nt++) {
                int col = goff + nt * 16 + (lane & 15);
                int row0 = mt * 16 + kgrp * 4;
                unsigned p01 = pkbf(ssp(acc[mt][nt][0]), ssp(acc[mt][nt][1]));
                unsigned p23 = pkbf(ssp(acc[mt][nt][2]), ssp(acc[mt][nt][3]));
                hL[(row0 + 0) * HSTR + col] = (short)(p01 & 0xffffu);
                hL[(row0 + 1) * HSTR + col] = (short)(p01 >> 16);
                hL[(row0 + 2) * HSTR + col] = (short)(p23 & 0xffffu);
                hL[(row0 + 3) * HSTR + col] = (short)(p23 >> 16);
            }
        }
    }
    __syncthreads();   // #2

    // ---- GEMM2: Wfilt = h @ W2 + b2 ----
    f32x4 acc2[4][2];
#pragma unroll
    for (int mt = 0; mt < 4; mt++) {
        acc2[mt][0] = (f32x4){b2v0, b2v0, b2v0, b2v0};
        acc2[mt][1] = (f32x4){b2v1, b2v1, b2v1, b2v1};
    }
#pragma unroll
    for (int kt = 0; kt < 4; kt++) {
        bf16x8 bf0 = *(const bf16x8*)&W2f[((kt * 8 + wid * 2 + 0) * 64 + lane) * 8];
        bf16x8 bf1 = *(const bf16x8*)&W2f[((kt * 8 + wid * 2 + 1) * 64 + lane) * 8];
#pragma unroll
        for (int mt = 0; mt < 4; mt++) {
            if (mt < MT) {
                bf16x8 af = *(const bf16x8*)&hL[(mt * 16 + rowA) * HSTR + kt * 32 + kgrp * 8];
                acc2[mt][0] = __builtin_amdgcn_mfma_f32_16x16x32_bf16(af, bf0, acc2[mt][0], 0, 0, 0);
                acc2[mt][1] = __builtin_amdgcn_mfma_f32_16x16x32_bf16(af, bf1, acc2[mt][1], 0, 0, 0);
            }
        }
    }
    __syncthreads();   // #3: all fijL/hL reads done; wfT may overlay

    // Wfilt -> wfT[g][j] (transposed): one aligned b64 per fragment pair
#pragma unroll
    for (int mt = 0; mt < 4; mt++) {
        if (mt < MT) {
#pragma unroll
            for (int nt = 0; nt < 2; nt++) {
                int col = goff + nt * 16 + (lane & 15);   // g
                int r0 = mt * 16 + kgrp * 4;              // j base
                u32x2 pk = (u32x2){pkbf(acc2[mt][nt][0], acc2[mt][nt][1]),
                                   pkbf(acc2[mt][nt][2], acc2[mt][nt][3])};
                *(u32x2*)&wfT[col * JSTR + r0] = pk;
            }
        }
    }
    __syncthreads();   // #4

    // ---- epilogue: vector wf reads in j, coalesced y, shfl-pair reduce ----
    int g = goff + (lane >> 1);      // each col covered by adjacent lane pair
    int half = lane & 1;             // j-block parity
    const float* yb = y + (size_t)b * NA * NF;
    float p = 0.0f;
    int Vp8 = (V + 7) >> 3;
    for (int jb = half; jb < Vp8; jb += 2) {
        int j0 = jb * 8;
        u32x4 wv = *(const u32x4*)&wfT[g * JSTR + j0];
#pragma unroll
        for (int e = 0; e < 8; e++) {
            int j = j0 + e;
            unsigned w16 = (e & 1) ? (wv[e >> 1] >> 16) : (wv[e >> 1] & 0xffffu);
            float wf = (j < V) ? bf2f((short)w16) : 0.0f;
            p = fmaf(yb[(size_t)cOff[j] + g], wf, p);
        }
    }
    p += __shfl_xor(p, 1, 64);
    if (half == 0) agg[(size_t)ba * NF + g] = p;
}

extern "C" void kernel_launch(void* const* d_in, const int* in_sizes, int n_in,
                              void* d_out, int out_size, void* d_ws, size_t ws_size,
                              hipStream_t stream) {
    const float* x    = (const float*)d_in[0];
    const float* rij  = (const float*)d_in[1];
    const float* fij  = (const float*)d_in[2];
    const int*   nbr  = (const int*)d_in[3];
    const int*   nmask = (const int*)d_in[4];     // bool -> int32 per harness
    const float* W_in2f = (const float*)d_in[5];
    const float* W1   = (const float*)d_in[6];
    const float* b1   = (const float*)d_in[7];
    const float* W2   = (const float*)d_in[8];
    const float* b2   = (const float*)d_in[9];
    const float* Wf2  = (const float*)d_in[10];
    const float* bf2  = (const float*)d_in[11];
    const float* Wd   = (const float*)d_in[12];
    const float* bd   = (const float*)d_in[13];

    float* out = (float*)d_out;
    float* y   = (float*)d_ws;                                       // 4 MB f32 scratch
    short* W1f   = (short*)((char*)d_ws + (size_t)NB * NA * NF * 4); // 16 KB
    short* W2f   = W1f + NS * NF;                                    // 32 KB
    short* Winff = W2f + NF * NF;                                    // 32 KB
    short* Wf2f  = Winff + NF * NF;                                  // 32 KB
    short* Wdf   = Wf2f + NF * NF;                                   // 32 KB

    const int rows = NB * NA;   // 8192

    k_prep<<<64, 256, 0, stream>>>(W1, W2, W_in2f, Wf2, Wd, W1f, W2f, Winff, Wf2f, Wdf);
    k_in2f_m<<<rows / 32, 256, 0, stream>>>(x, Winff, y);
    k_conv<<<rows, 256, 0, stream>>>(fij, rij, nbr, nmask, y, W1f, b1, W2f, b2, out);
    k_out_m<<<rows / 32, 256, 0, stream>>>(out, Wf2f, bf2, Wdf, bd);
}